// Round 3
// baseline (552.853 us; speedup 1.0000x reference)
//
#include <hip/hip_runtime.h>

typedef unsigned short ushort_t;
typedef __attribute__((ext_vector_type(8))) short short8;
typedef __attribute__((ext_vector_type(4))) float floatx4;

#define DD 256
#define LL 3
#define GG 4
#define KK 128
#define UU 64
#define OUTN 10
#define HSTRIDE 264   // 256 + 8 bf16 pad; 528B row stride (odd multiple of 16B -> per-row bank-slot rotation)
#define MROWS 32      // rows per block (4-wave blocks -> 5 blocks/CU)

__device__ __forceinline__ ushort_t f2bf(float f) {
  unsigned u = __builtin_bit_cast(unsigned, f);
  u = (u + 0x7FFFu + ((u >> 16) & 1u)) >> 16;
  return (ushort_t)u;
}

// pack two f32 -> two bf16: 2 adds + 1 v_perm_b32
__device__ __forceinline__ unsigned pack_bf2(float lo, float hi) {
  unsigned a = __builtin_bit_cast(unsigned, hi) + 0x8000u;
  unsigned b = __builtin_bit_cast(unsigned, lo) + 0x8000u;
  return __builtin_amdgcn_perm(a, b, 0x07060302u);
}

// tanh(x) = 1 - 2/(e^{2x}+1); branch-free, exact at overflow
__device__ __forceinline__ float fast_tanh(float x) {
  float e = __builtin_amdgcn_exp2f(x * 2.885390081777927f);
  return __builtin_fmaf(-2.0f, __builtin_amdgcn_rcpf(e + 1.0f), 1.0f);
}

// AT[l][n][k] = sum_{j: idx[l,g,j]==k} W[l,g,j,u]  (n = g*64+u), bf16.
// WoT[n][k] = W_out[k][n] (n<10 else 0), 16x256 bf16.
__global__ __launch_bounds__(256) void prep_kernel(
    const int* __restrict__ idx, const float* __restrict__ W,
    const float* __restrict__ Wout, ushort_t* __restrict__ AT,
    ushort_t* __restrict__ WoT) {
  int b = blockIdx.x;
  int t = threadIdx.x;
  if (b < LL * DD) {
    int l = b >> 8, n = b & 255, g = n >> 6, u = n & 63;
    __shared__ int sidx[KK];
    __shared__ float sw[KK];
    if (t < KK) {
      sidx[t] = idx[(l * GG + g) * KK + t];
      sw[t]   = W[((size_t)((l * GG + g) * KK + t)) * UU + u];
    }
    __syncthreads();
    float s = 0.f;
#pragma unroll 8
    for (int j = 0; j < KK; j++) s += (sidx[j] == t) ? sw[j] : 0.f;
    AT[(b << 8) | t] = f2bf(s);
  } else {
    int e2 = (b - LL * DD) * 256 + t;
    int n = e2 >> 8, k = e2 & 255;
    WoT[e2] = (n < OUTN) ? f2bf(Wout[k * OUTN + n]) : (ushort_t)0;
  }
}

// 16x16x32 MFMA, operand-swap: Aop = AT rows (u-dim), Bop = h rows (m-dim).
// Frag: index = lane&15, k = (lane>>4)*8 + j within a 32-k chunk.
// D: col = lane&15 -> m_local, row = (lane>>4)*4 + reg -> u_local.
// Block = 4 waves, 32 rows. Wave: wm = wave>>1 (16 rows), wn = wave&1 (128 cols, NT=8).
// Each b-read (one ds_read_b128) feeds 8 MFMAs; b staggered depth-1.
__global__ __launch_bounds__(256, 5) void fused_kernel(
    const float* __restrict__ x, const float* __restrict__ bias,
    const float* __restrict__ bout, const ushort_t* __restrict__ AT,
    const ushort_t* __restrict__ WoT, float* __restrict__ out) {
  __shared__ ushort_t hbuf[MROWS * HSTRIDE];  // 16896 B -> 5 blocks/CU (84.5 KB)

  const int tid  = threadIdx.x;
  const int wave = tid >> 6;     // 0..3
  const int lane = tid & 63;
  const int quad = lane >> 4;
  const int l16  = lane & 15;
  const int wm   = wave >> 1;    // 0..1 : rows [wm*16, +16)
  const int wn   = wave & 1;     // 0..1 : cols [wn*128, +128)
  const long row0 = (long)blockIdx.x * MROWS;

  // ---- stage x tile (32 x 256 fp32) -> bf16 LDS ----
  const float4* xv = (const float4*)(x + row0 * DD);
#pragma unroll
  for (int i = 0; i < 8; i++) {
    int f  = tid + i * 256;      // 0..2047 float4s, 64 per row
    int r  = f >> 6;
    int c4 = f & 63;
    float4 v = xv[r * 64 + c4];
    uint2 w;
    w.x = pack_bf2(v.x, v.y);
    w.y = pack_bf2(v.z, v.w);
    *(uint2*)&hbuf[r * HSTRIDE + c4 * 4] = w;
  }
  __syncthreads();

  // ---- 3 levels ----
#pragma unroll 1
  for (int l = 0; l < 3; l++) {
    const ushort_t* Ab   = AT + l * (DD * DD) + (wn * 128 + l16) * DD + quad * 8;
    const ushort_t* hsrc = hbuf + (wm * 16 + l16) * HSTRIDE + quad * 8;

    floatx4 acc[8];  // 8 n-tiles of 16 cols; bias folded into init
#pragma unroll
    for (int nt = 0; nt < 8; nt++) {
      float4 bv = *(const float4*)&bias[l * DD + wn * 128 + nt * 16 + quad * 4];
      floatx4 ini = {bv.x, bv.y, bv.z, bv.w};
      acc[nt] = ini;
    }

    short8 bf = *(const short8*)&hsrc[0];
#pragma unroll
    for (int ks = 0; ks < 8; ks++) {
      short8 af[8];
#pragma unroll
      for (int nt = 0; nt < 8; nt++)
        af[nt] = *(const short8*)&Ab[nt * 16 * DD + ks * 32];
      short8 bfn;
      if (ks < 7) bfn = *(const short8*)&hsrc[(ks + 1) * 32];  // depth-1 stagger
#pragma unroll
      for (int nt = 0; nt < 8; nt++)
        acc[nt] = __builtin_amdgcn_mfma_f32_16x16x32_bf16(af[nt], bf, acc[nt], 0, 0, 0);
      bf = bfn;
    }
    __syncthreads();  // all hbuf reads done before overwrite

    // epilogue: lane owns row m = wm*16+l16; writes 8B per n-tile
#pragma unroll
    for (int nt = 0; nt < 8; nt++) {
      uint2 w;
      w.x = pack_bf2(fast_tanh(acc[nt][0]), fast_tanh(acc[nt][1]));
      w.y = pack_bf2(fast_tanh(acc[nt][2]), fast_tanh(acc[nt][3]));
      *(uint2*)&hbuf[(wm * 16 + l16) * HSTRIDE + wn * 128 + nt * 16 + quad * 4] = w;
    }
    __syncthreads();
  }

  // ---- final: waves 0,1 handle rows [wave*16,+16); Aop = WoT rows (o) ----
  if (wave < 2) {
    short8 wof[8];
#pragma unroll
    for (int ks = 0; ks < 8; ks++)
      wof[ks] = *(const short8*)&WoT[l16 * DD + ks * 32 + quad * 8];

    floatx4 accf = {0.f, 0.f, 0.f, 0.f};
#pragma unroll
    for (int ks = 0; ks < 8; ks++) {
      short8 bfr = *(const short8*)&hbuf[(wave * 16 + l16) * HSTRIDE + ks * 32 + quad * 8];
      accf = __builtin_amdgcn_mfma_f32_16x16x32_bf16(wof[ks], bfr, accf, 0, 0, 0);
    }
    const long obase = (row0 + wave * 16 + l16) * OUTN;
    if (quad < 2) {
      float4 p = {accf[0] + bout[quad * 4 + 0], accf[1] + bout[quad * 4 + 1],
                  accf[2] + bout[quad * 4 + 2], accf[3] + bout[quad * 4 + 3]};
      *(float4*)&out[obase + quad * 4] = p;
    } else if (quad == 2) {
      float2 p = {accf[0] + bout[8], accf[1] + bout[9]};
      *(float2*)&out[obase + 8] = p;
    }
  }
}

extern "C" void kernel_launch(void* const* d_in, const int* in_sizes, int n_in,
                              void* d_out, int out_size, void* d_ws, size_t ws_size,
                              hipStream_t stream) {
  const float* x    = (const float*)d_in[0];   // (131072, 256) fp32
  const int*   idx  = (const int*)d_in[1];     // (3, 4, 128) int32
  const float* W    = (const float*)d_in[2];   // (3, 4, 128, 64) fp32
  const float* b    = (const float*)d_in[3];   // (3, 4, 64) fp32
  const float* Wout = (const float*)d_in[4];   // (256, 10) fp32
  const float* bout = (const float*)d_in[5];   // (10,) fp32
  float* out = (float*)d_out;                  // (131072, 10) fp32

  ushort_t* AT  = (ushort_t*)d_ws;             // 3*256*256 bf16
  ushort_t* WoT = AT + LL * DD * DD;           // 16*256 bf16

  prep_kernel<<<LL * DD + 16, 256, 0, stream>>>(idx, W, Wout, AT, WoT);
  fused_kernel<<<131072 / MROWS, 256, 0, stream>>>(x, b, bout, AT, WoT, out);
}

// Round 4
// 289.435 us; speedup vs baseline: 1.9101x; 1.9101x over previous
//
#include <hip/hip_runtime.h>

typedef unsigned short ushort_t;
typedef __attribute__((ext_vector_type(8))) short short8;
typedef __attribute__((ext_vector_type(4))) float floatx4;

#define DD 256
#define LL 3
#define GG 4
#define KK 128
#define UU 64
#define OUTN 10
#define HSTRIDE 264   // 256 + 8 bf16 pad; 528B row stride
#define MROWS 64      // rows per block; hbuf[2] ping-pong -> 67.5 KB -> 2 blocks/CU

__device__ __forceinline__ ushort_t f2bf(float f) {
  unsigned u = __builtin_bit_cast(unsigned, f);
  u = (u + 0x7FFFu + ((u >> 16) & 1u)) >> 16;
  return (ushort_t)u;
}

// pack two f32 -> two bf16: 2 adds + 1 v_perm_b32
__device__ __forceinline__ unsigned pack_bf2(float lo, float hi) {
  unsigned a = __builtin_bit_cast(unsigned, hi) + 0x8000u;
  unsigned b = __builtin_bit_cast(unsigned, lo) + 0x8000u;
  return __builtin_amdgcn_perm(a, b, 0x07060302u);
}

// tanh(x) = 1 - 2/(e^{2x}+1); branch-free, exact at overflow
__device__ __forceinline__ float fast_tanh(float x) {
  float e = __builtin_amdgcn_exp2f(x * 2.885390081777927f);
  return __builtin_fmaf(-2.0f, __builtin_amdgcn_rcpf(e + 1.0f), 1.0f);
}

// AT[l][n][k] = sum_{j: idx[l,g,j]==k} W[l,g,j,u]  (n = g*64+u), bf16.
// WoT[n][k] = W_out[k][n] (n<10 else 0), 16x256 bf16.
__global__ __launch_bounds__(256) void prep_kernel(
    const int* __restrict__ idx, const float* __restrict__ W,
    const float* __restrict__ Wout, ushort_t* __restrict__ AT,
    ushort_t* __restrict__ WoT) {
  int b = blockIdx.x;
  int t = threadIdx.x;
  if (b < LL * DD) {
    int l = b >> 8, n = b & 255, g = n >> 6, u = n & 63;
    __shared__ int sidx[KK];
    __shared__ float sw[KK];
    if (t < KK) {
      sidx[t] = idx[(l * GG + g) * KK + t];
      sw[t]   = W[((size_t)((l * GG + g) * KK + t)) * UU + u];
    }
    __syncthreads();
    float s = 0.f;
#pragma unroll 8
    for (int j = 0; j < KK; j++) s += (sidx[j] == t) ? sw[j] : 0.f;
    AT[(b << 8) | t] = f2bf(s);
  } else {
    int e2 = (b - LL * DD) * 256 + t;
    int n = e2 >> 8, k = e2 & 255;
    WoT[e2] = (n < OUTN) ? f2bf(Wout[k * OUTN + n]) : (ushort_t)0;
  }
}

// 16x16x32 MFMA, operand-swap: Aop = AT rows (u-dim), Bop = h rows (m-dim).
// Frag: index = lane&15, k = (lane>>4)*8 + j within a 32-k chunk.
// D: col = lane&15 -> m_local, row = (lane>>4)*4 + reg -> u_local.
// 8 waves; wave w owns ALL 64 rows x cols [w*32, w*32+32): mt=4, nt=2.
// Per ks: 4 b-reads (reuse 2x) + 2 a-reads (reuse 4x) + 8 MFMAs; full-ks
// depth-1 pipeline (next ks's 6 frags issued before current MFMAs).
// Ping-pong LDS: level l reads hbuf[l&1], epilogue writes hbuf[(l+1)&1];
// ONE barrier per level.
__global__ __launch_bounds__(512, 4) void fused_kernel(
    const float* __restrict__ x, const float* __restrict__ bias,
    const float* __restrict__ bout, const ushort_t* __restrict__ AT,
    const ushort_t* __restrict__ WoT, float* __restrict__ out) {
  __shared__ ushort_t hbuf[2][MROWS * HSTRIDE];  // 2 x 33792 B = 67584 B

  const int tid  = threadIdx.x;
  const int wave = tid >> 6;     // 0..7 : cols [wave*32, +32)
  const int lane = tid & 63;
  const int quad = lane >> 4;
  const int l16  = lane & 15;
  const long row0 = (long)blockIdx.x * MROWS;

  // ---- stage x tile (64 x 256 fp32) -> bf16 LDS buf0 ----
  const float4* xv = (const float4*)(x + row0 * DD);
#pragma unroll
  for (int i = 0; i < 8; i++) {
    int f  = tid + i * 512;      // 0..4095 float4s, 64 per row
    int r  = f >> 6;
    int c4 = f & 63;
    float4 v = xv[r * 64 + c4];
    uint2 w;
    w.x = pack_bf2(v.x, v.y);
    w.y = pack_bf2(v.z, v.w);
    *(uint2*)&hbuf[0][r * HSTRIDE + c4 * 4] = w;
  }
  __syncthreads();

  // ---- 3 levels ----
#pragma unroll 1
  for (int l = 0; l < 3; l++) {
    const int pr = l & 1, pw = pr ^ 1;
    const ushort_t* Ab = AT + l * (DD * DD) + (wave * 32 + l16) * DD + quad * 8;
    const ushort_t* hs = hbuf[pr] + l16 * HSTRIDE + quad * 8;

    floatx4 acc[4][2];  // [mt][nt]; bias folded into init
#pragma unroll
    for (int nt = 0; nt < 2; nt++) {
      float4 bv = *(const float4*)&bias[l * DD + wave * 32 + nt * 16 + quad * 4];
      floatx4 ini = {bv.x, bv.y, bv.z, bv.w};
#pragma unroll
      for (int mt = 0; mt < 4; mt++) acc[mt][nt] = ini;
    }

    short8 a0 = *(const short8*)&Ab[0];
    short8 a1 = *(const short8*)&Ab[16 * DD];
    short8 b0 = *(const short8*)&hs[0 * 16 * HSTRIDE];
    short8 b1 = *(const short8*)&hs[1 * 16 * HSTRIDE];
    short8 b2 = *(const short8*)&hs[2 * 16 * HSTRIDE];
    short8 b3 = *(const short8*)&hs[3 * 16 * HSTRIDE];

#pragma unroll
    for (int ks = 0; ks < 8; ks++) {
      short8 na0, na1, nb0, nb1, nb2, nb3;
      if (ks < 7) {
        const int o = (ks + 1) * 32;
        nb0 = *(const short8*)&hs[0 * 16 * HSTRIDE + o];
        nb1 = *(const short8*)&hs[1 * 16 * HSTRIDE + o];
        nb2 = *(const short8*)&hs[2 * 16 * HSTRIDE + o];
        nb3 = *(const short8*)&hs[3 * 16 * HSTRIDE + o];
        na0 = *(const short8*)&Ab[o];
        na1 = *(const short8*)&Ab[16 * DD + o];
      }
      acc[0][0] = __builtin_amdgcn_mfma_f32_16x16x32_bf16(a0, b0, acc[0][0], 0, 0, 0);
      acc[0][1] = __builtin_amdgcn_mfma_f32_16x16x32_bf16(a1, b0, acc[0][1], 0, 0, 0);
      acc[1][0] = __builtin_amdgcn_mfma_f32_16x16x32_bf16(a0, b1, acc[1][0], 0, 0, 0);
      acc[1][1] = __builtin_amdgcn_mfma_f32_16x16x32_bf16(a1, b1, acc[1][1], 0, 0, 0);
      acc[2][0] = __builtin_amdgcn_mfma_f32_16x16x32_bf16(a0, b2, acc[2][0], 0, 0, 0);
      acc[2][1] = __builtin_amdgcn_mfma_f32_16x16x32_bf16(a1, b2, acc[2][1], 0, 0, 0);
      acc[3][0] = __builtin_amdgcn_mfma_f32_16x16x32_bf16(a0, b3, acc[3][0], 0, 0, 0);
      acc[3][1] = __builtin_amdgcn_mfma_f32_16x16x32_bf16(a1, b3, acc[3][1], 0, 0, 0);
      a0 = na0; a1 = na1;
      b0 = nb0; b1 = nb1; b2 = nb2; b3 = nb3;
    }

    // epilogue: lane owns row m = mt*16+l16, cols wave*32+nt*16+quad*4..+3
    // writes go to the OTHER buffer -> no pre-write barrier needed
#pragma unroll
    for (int mt = 0; mt < 4; mt++) {
#pragma unroll
      for (int nt = 0; nt < 2; nt++) {
        uint2 w;
        w.x = pack_bf2(fast_tanh(acc[mt][nt][0]), fast_tanh(acc[mt][nt][1]));
        w.y = pack_bf2(fast_tanh(acc[mt][nt][2]), fast_tanh(acc[mt][nt][3]));
        *(uint2*)&hbuf[pw][(mt * 16 + l16) * HSTRIDE + wave * 32 + nt * 16 + quad * 4] = w;
      }
    }
    __syncthreads();  // writes to hbuf[pw] visible before next level reads it
  }

  // ---- final: h is in hbuf[1]; waves 0..3 handle rows [wave*16,+16) ----
  if (wave < 4) {
    short8 wof[8];
#pragma unroll
    for (int ks = 0; ks < 8; ks++)
      wof[ks] = *(const short8*)&WoT[l16 * DD + ks * 32 + quad * 8];

    floatx4 accf = {0.f, 0.f, 0.f, 0.f};
#pragma unroll
    for (int ks = 0; ks < 8; ks++) {
      short8 bfr = *(const short8*)&hbuf[1][(wave * 16 + l16) * HSTRIDE + ks * 32 + quad * 8];
      accf = __builtin_amdgcn_mfma_f32_16x16x32_bf16(wof[ks], bfr, accf, 0, 0, 0);
    }
    const long obase = (row0 + wave * 16 + l16) * OUTN;
    if (quad < 2) {
      float4 p = {accf[0] + bout[quad * 4 + 0], accf[1] + bout[quad * 4 + 1],
                  accf[2] + bout[quad * 4 + 2], accf[3] + bout[quad * 4 + 3]};
      *(float4*)&out[obase + quad * 4] = p;
    } else if (quad == 2) {
      float2 p = {accf[0] + bout[8], accf[1] + bout[9]};
      *(float2*)&out[obase + 8] = p;
    }
  }
}

extern "C" void kernel_launch(void* const* d_in, const int* in_sizes, int n_in,
                              void* d_out, int out_size, void* d_ws, size_t ws_size,
                              hipStream_t stream) {
  const float* x    = (const float*)d_in[0];   // (131072, 256) fp32
  const int*   idx  = (const int*)d_in[1];     // (3, 4, 128) int32
  const float* W    = (const float*)d_in[2];   // (3, 4, 128, 64) fp32
  const float* b    = (const float*)d_in[3];   // (3, 4, 64) fp32
  const float* Wout = (const float*)d_in[4];   // (256, 10) fp32
  const float* bout = (const float*)d_in[5];   // (10,) fp32
  float* out = (float*)d_out;                  // (131072, 10) fp32

  ushort_t* AT  = (ushort_t*)d_ws;             // 3*256*256 bf16
  ushort_t* WoT = AT + LL * DD * DD;           // 16*256 bf16

  prep_kernel<<<LL * DD + 16, 256, 0, stream>>>(idx, W, Wout, AT, WoT);
  fused_kernel<<<131072 / MROWS, 512, 0, stream>>>(x, b, bout, AT, WoT, out);
}

// Round 6
// 271.469 us; speedup vs baseline: 2.0365x; 1.0662x over previous
//
#include <hip/hip_runtime.h>

typedef unsigned short ushort_t;
typedef __attribute__((ext_vector_type(8))) short short8;
typedef __attribute__((ext_vector_type(4))) float floatx4;

#define DD 256
#define LL 3
#define GG 4
#define KK 128
#define UU 64
#define OUTN 10
#define HSTRIDE 264   // 256 + 8 bf16 pad; 528B row stride
#define MROWS 128     // rows per block; 4-wave blocks, 67.5 KB -> 2 blocks/CU

__device__ __forceinline__ ushort_t f2bf(float f) {
  unsigned u = __builtin_bit_cast(unsigned, f);
  u = (u + 0x7FFFu + ((u >> 16) & 1u)) >> 16;
  return (ushort_t)u;
}

// pack two f32 -> two bf16: 2 adds + 1 v_perm_b32
__device__ __forceinline__ unsigned pack_bf2(float lo, float hi) {
  unsigned a = __builtin_bit_cast(unsigned, hi) + 0x8000u;
  unsigned b = __builtin_bit_cast(unsigned, lo) + 0x8000u;
  return __builtin_amdgcn_perm(a, b, 0x07060302u);
}

// tanh(x) = 1 - 2/(e^{2x}+1); branch-free, exact at overflow
__device__ __forceinline__ float fast_tanh(float x) {
  float e = __builtin_amdgcn_exp2f(x * 2.885390081777927f);
  return __builtin_fmaf(-2.0f, __builtin_amdgcn_rcpf(e + 1.0f), 1.0f);
}

// AT[l][n][k] = sum_{j: idx[l,g,j]==k} W[l,g,j,u]  (n = g*64+u), bf16.
// WoT[n][k] = W_out[k][n] (n<10 else 0), 16x256 bf16.
__global__ __launch_bounds__(256) void prep_kernel(
    const int* __restrict__ idx, const float* __restrict__ W,
    const float* __restrict__ Wout, ushort_t* __restrict__ AT,
    ushort_t* __restrict__ WoT) {
  int b = blockIdx.x;
  int t = threadIdx.x;
  if (b < LL * DD) {
    int l = b >> 8, n = b & 255, g = n >> 6, u = n & 63;
    __shared__ int sidx[KK];
    __shared__ float sw[KK];
    if (t < KK) {
      sidx[t] = idx[(l * GG + g) * KK + t];
      sw[t]   = W[((size_t)((l * GG + g) * KK + t)) * UU + u];
    }
    __syncthreads();
    float s = 0.f;
#pragma unroll 8
    for (int j = 0; j < KK; j++) s += (sidx[j] == t) ? sw[j] : 0.f;
    AT[(b << 8) | t] = f2bf(s);
  } else {
    int e2 = (b - LL * DD) * 256 + t;
    int n = e2 >> 8, k = e2 & 255;
    WoT[e2] = (n < OUTN) ? f2bf(Wout[k * OUTN + n]) : (ushort_t)0;
  }
}

// 16x16x32 MFMA, operand-swap: Aop = AT rows (u-dim), Bop = h rows (m-dim).
// Frag: index = lane&15, k = (lane>>4)*8 + j within a 32-k chunk.
// D: col = lane&15 -> m_local, row = (lane>>4)*4 + reg -> u_local.
// Block = 4 waves, 128 rows. Wave w owns ALL 128 rows x cols [w*64, +64):
// MT=8, NT=4 -> per ks: 4 a-loads (L2) + 8 b-reads (LDS, each reused 4x)
// + 32 MFMAs (~160 cy cover >= L2 latency). acc = 128 AGPR; ~208 unified
// regs -> 8 waves/CU; latency hidden by per-wave compute depth, not TLP.
__global__ __launch_bounds__(256, 2) void fused_kernel(
    const float* __restrict__ x, const float* __restrict__ bias,
    const float* __restrict__ bout, const ushort_t* __restrict__ AT,
    const ushort_t* __restrict__ WoT, float* __restrict__ out) {
  __shared__ ushort_t hbuf[MROWS * HSTRIDE];  // 67584 B -> 2 blocks/CU

  const int tid  = threadIdx.x;
  const int wave = tid >> 6;     // 0..3 : cols [wave*64, +64)
  const int lane = tid & 63;
  const int quad = lane >> 4;
  const int l16  = lane & 15;
  const long row0 = (long)blockIdx.x * MROWS;

  // ---- stage x tile (128 x 256 fp32) -> bf16 LDS ----
  const float4* xv = (const float4*)(x + row0 * DD);
#pragma unroll
  for (int i = 0; i < 32; i++) {
    int f  = tid + i * 256;      // 0..8191 float4s, 64 per row
    int r  = f >> 6;
    int c4 = f & 63;
    float4 v = xv[r * 64 + c4];
    uint2 w;
    w.x = pack_bf2(v.x, v.y);
    w.y = pack_bf2(v.z, v.w);
    *(uint2*)&hbuf[r * HSTRIDE + c4 * 4] = w;
  }
  __syncthreads();

  // ---- 3 levels ----
#pragma unroll 1
  for (int l = 0; l < 3; l++) {
    const ushort_t* Ab   = AT + l * (DD * DD) + (wave * 64 + l16) * DD + quad * 8;
    const ushort_t* hsrc = hbuf + l16 * HSTRIDE + quad * 8;

    floatx4 acc[8][4];  // [mt][nt]; bias folded into init
#pragma unroll
    for (int nt = 0; nt < 4; nt++) {
      float4 bv = *(const float4*)&bias[l * DD + wave * 64 + nt * 16 + quad * 4];
      floatx4 ini = {bv.x, bv.y, bv.z, bv.w};
#pragma unroll
      for (int mt = 0; mt < 8; mt++) acc[mt][nt] = ini;
    }

    short8 wf[4], wfn[4];
#pragma unroll
    for (int nt = 0; nt < 4; nt++) wf[nt] = *(const short8*)&Ab[nt * 16 * DD];

#pragma unroll
    for (int ks = 0; ks < 8; ks++) {
      if (ks < 7) {
#pragma unroll
        for (int nt = 0; nt < 4; nt++)
          wfn[nt] = *(const short8*)&Ab[nt * 16 * DD + (ks + 1) * 32];
      }
      // rolling b: only 2 b frags live at once; each b feeds 4 MFMAs
      short8 bfc = *(const short8*)&hsrc[0 * 16 * HSTRIDE + ks * 32];
#pragma unroll
      for (int mt = 0; mt < 8; mt++) {
        short8 bfn;
        if (mt < 7) bfn = *(const short8*)&hsrc[(mt + 1) * 16 * HSTRIDE + ks * 32];
        acc[mt][0] = __builtin_amdgcn_mfma_f32_16x16x32_bf16(wf[0], bfc, acc[mt][0], 0, 0, 0);
        acc[mt][1] = __builtin_amdgcn_mfma_f32_16x16x32_bf16(wf[1], bfc, acc[mt][1], 0, 0, 0);
        acc[mt][2] = __builtin_amdgcn_mfma_f32_16x16x32_bf16(wf[2], bfc, acc[mt][2], 0, 0, 0);
        acc[mt][3] = __builtin_amdgcn_mfma_f32_16x16x32_bf16(wf[3], bfc, acc[mt][3], 0, 0, 0);
        bfc = bfn;
      }
#pragma unroll
      for (int nt = 0; nt < 4; nt++) wf[nt] = wfn[nt];
    }
    __syncthreads();  // all hbuf reads done before overwrite

    // epilogue: lane owns row m = mt*16+l16, cols wave*64+nt*16+quad*4..+3
#pragma unroll
    for (int mt = 0; mt < 8; mt++) {
#pragma unroll
      for (int nt = 0; nt < 4; nt++) {
        uint2 w;
        w.x = pack_bf2(fast_tanh(acc[mt][nt][0]), fast_tanh(acc[mt][nt][1]));
        w.y = pack_bf2(fast_tanh(acc[mt][nt][2]), fast_tanh(acc[mt][nt][3]));
        *(uint2*)&hbuf[(mt * 16 + l16) * HSTRIDE + wave * 64 + nt * 16 + quad * 4] = w;
      }
    }
    __syncthreads();
  }

  // ---- final: Aop = WoT rows (o); each wave does 2 chunks of 16 rows ----
  short8 wof[8];
#pragma unroll
  for (int ks = 0; ks < 8; ks++)
    wof[ks] = *(const short8*)&WoT[l16 * DD + ks * 32 + quad * 8];

#pragma unroll
  for (int c = 0; c < 2; c++) {
    const int mrow = wave * 32 + c * 16 + l16;
    floatx4 accf = {0.f, 0.f, 0.f, 0.f};
#pragma unroll
    for (int ks = 0; ks < 8; ks++) {
      short8 bfr = *(const short8*)&hbuf[mrow * HSTRIDE + ks * 32 + quad * 8];
      accf = __builtin_amdgcn_mfma_f32_16x16x32_bf16(wof[ks], bfr, accf, 0, 0, 0);
    }
    const long obase = (row0 + mrow) * OUTN;
    if (quad < 2) {
      float4 p = {accf[0] + bout[quad * 4 + 0], accf[1] + bout[quad * 4 + 1],
                  accf[2] + bout[quad * 4 + 2], accf[3] + bout[quad * 4 + 3]};
      *(float4*)&out[obase + quad * 4] = p;
    } else if (quad == 2) {
      float2 p = {accf[0] + bout[8], accf[1] + bout[9]};
      *(float2*)&out[obase + 8] = p;
    }
  }
}

extern "C" void kernel_launch(void* const* d_in, const int* in_sizes, int n_in,
                              void* d_out, int out_size, void* d_ws, size_t ws_size,
                              hipStream_t stream) {
  const float* x    = (const float*)d_in[0];   // (131072, 256) fp32
  const int*   idx  = (const int*)d_in[1];     // (3, 4, 128) int32
  const float* W    = (const float*)d_in[2];   // (3, 4, 128, 64) fp32
  const float* b    = (const float*)d_in[3];   // (3, 4, 64) fp32
  const float* Wout = (const float*)d_in[4];   // (256, 10) fp32
  const float* bout = (const float*)d_in[5];   // (10,) fp32
  float* out = (float*)d_out;                  // (131072, 10) fp32

  ushort_t* AT  = (ushort_t*)d_ws;             // 3*256*256 bf16
  ushort_t* WoT = AT + LL * DD * DD;           // 16*256 bf16

  prep_kernel<<<LL * DD + 16, 256, 0, stream>>>(idx, W, Wout, AT, WoT);
  fused_kernel<<<131072 / MROWS, 256, 0, stream>>>(x, b, bout, AT, WoT, out);
}